// Round 12
// baseline (930.210 us; speedup 1.0000x reference)
//
#include <hip/hip_runtime.h>
#include <cstdint>
#include <cstddef>

#define NBATCH 128
#define NCH    256
#define NHW    1024
#define NTIME  64
#define NCLS   128

typedef _Float16 f16_t;
typedef _Float16 f16x8 __attribute__((ext_vector_type(8)));
typedef short bf16x8 __attribute__((ext_vector_type(8)));
typedef short bf16x4 __attribute__((ext_vector_type(4)));
typedef float f32x4 __attribute__((ext_vector_type(4)));
typedef unsigned short ushort_t;

__device__ __forceinline__ ushort_t f2bf(float x){
  unsigned u = __builtin_bit_cast(unsigned, x);
  unsigned r = (u + 0x7FFFu + ((u>>16)&1u)) >> 16;
  return (ushort_t)r;
}
__device__ __forceinline__ float sig_(float x){
  x = fminf(30.f, fmaxf(-30.f, x));
  return 1.f/(1.f+__expf(-x));
}
__device__ __forceinline__ float tanh_(float x){
  x = fminf(15.f, fmaxf(-15.f, x));
  float e = __expf(2.f*x);
  return (e-1.f)/(e+1.f);
}

// ---------------- K0: row sums of A -> S[b*64+t] ----------------
__global__ __launch_bounds__(256) void k_rowsum(const float* __restrict__ A, float* __restrict__ S){
  int row = blockIdx.x;
  const float4* a4 = (const float4*)(A + (size_t)row*NHW);
  float4 v = a4[threadIdx.x];
  float s = v.x+v.y+v.z+v.w;
  #pragma unroll
  for (int off=32; off>0; off>>=1) s += __shfl_down(s, off, 64);
  __shared__ float wsum[4];
  int lane = threadIdx.x & 63, w = threadIdx.x >> 6;
  if (lane==0) wsum[w] = s;
  __syncthreads();
  if (threadIdx.x==0) S[row] = wsum[0]+wsum[1]+wsum[2]+wsum[3];
}

// ---------------- weight converts ----------------
__global__ __launch_bounds__(256) void k_convw(const float* __restrict__ src, ushort_t* __restrict__ dst, int n){
  int i = blockIdx.x*256 + threadIdx.x;
  if (i < n) dst[i] = f2bf(src[i]);
}
__global__ __launch_bounds__(256) void k_convh(const float* __restrict__ src, f16_t* __restrict__ dst, int n){
  int i = blockIdx.x*256 + threadIdx.x;
  if (i < n) dst[i] = (f16_t)src[i];
}

// ---------------- K1: attention pooling via MFMA ----------------
__global__ __launch_bounds__(256) void k_pool_mfma(const float* __restrict__ feat, const float* __restrict__ A,
    const float* __restrict__ S, ushort_t* __restrict__ Cbf){
  __shared__ ushort_t As_[64*40];
  __shared__ ushort_t Fs_[128*40];
  __shared__ float sinvs[64];
  int b = blockIdx.x >> 1, ch = blockIdx.x & 1, c0 = ch*128;
  int tid = threadIdx.x, wave = tid>>6, lane = tid&63;
  if (tid < 64) sinvs[tid] = 1.f / S[b*64 + tid];
  f32x4 acc[4][2] = {};
  int lr = lane & 15, lk = (lane>>4)*8;
  for (int k0=0;k0<NHW;k0+=32){
    __syncthreads();
    #pragma unroll
    for (int i=0;i<2;i++){
      int c = tid + i*256, r = c>>3, kq = c&7;
      float4 v = *(const float4*)(A + ((size_t)(b*64+r))*NHW + k0 + kq*4);
      bf16x4 p; p[0]=(short)f2bf(v.x); p[1]=(short)f2bf(v.y); p[2]=(short)f2bf(v.z); p[3]=(short)f2bf(v.w);
      *(bf16x4*)&As_[r*40 + kq*4] = p;
    }
    #pragma unroll
    for (int i=0;i<4;i++){
      int c = tid + i*256, r = c>>3, kq = c&7;
      float4 v = *(const float4*)(feat + ((size_t)(b*256+c0+r))*NHW + k0 + kq*4);
      bf16x4 p; p[0]=(short)f2bf(v.x); p[1]=(short)f2bf(v.y); p[2]=(short)f2bf(v.z); p[3]=(short)f2bf(v.w);
      *(bf16x4*)&Fs_[r*40 + kq*4] = p;
    }
    __syncthreads();
    bf16x8 af[4], bg[2];
    #pragma unroll
    for (int m=0;m<4;m++) af[m] = *(const bf16x8*)&As_[(m*16 + lr)*40 + lk];
    #pragma unroll
    for (int n=0;n<2;n++) bg[n] = *(const bf16x8*)&Fs_[(wave*32 + n*16 + lr)*40 + lk];
    #pragma unroll
    for (int m=0;m<4;m++)
      #pragma unroll
      for (int n=0;n<2;n++)
        acc[m][n] = __builtin_amdgcn_mfma_f32_16x16x32_bf16(af[m], bg[n], acc[m][n], 0, 0, 0);
  }
  #pragma unroll
  for (int m=0;m<4;m++)
    #pragma unroll
    for (int n=0;n<2;n++)
      #pragma unroll
      for (int j=0;j<4;j++){
        int t = m*16 + (lane>>4)*4 + j;
        int c = c0 + wave*32 + n*16 + lr;
        Cbf[((size_t)t*NBATCH + b)*NCH + c] = f2bf(acc[m][n][j] * sinvs[t]);
      }
}

// ---------------- generic bf16 MFMA GEMM: out[M][N]fp32 = Xbf[M][K] @ Wbf[N][K]^T + ba(+bb) ---
__global__ __launch_bounds__(256) void k_gemm_bf(const ushort_t* __restrict__ X, const ushort_t* __restrict__ W,
    const float* __restrict__ ba, const float* __restrict__ bb, float* __restrict__ out, int N, int K){
  __shared__ ushort_t Xs[128*40];
  __shared__ ushort_t Ws[128*40];
  int n0 = blockIdx.x*128, m0 = blockIdx.y*128;
  int tid = threadIdx.x, wave = tid>>6, lane = tid&63;
  int wr = wave>>1, wc = wave&1;
  int lr = lane & 15, lk = (lane>>4)*8;
  f32x4 acc[4][4] = {};
  for (int k0=0;k0<K;k0+=32){
    __syncthreads();
    #pragma unroll
    for (int i=0;i<2;i++){
      int c = tid + i*256, r = c>>2, kb = c&3;
      *(bf16x8*)&Xs[r*40 + kb*8] = *(const bf16x8*)(X + (size_t)(m0+r)*K + k0 + kb*8);
      *(bf16x8*)&Ws[r*40 + kb*8] = *(const bf16x8*)(W + (size_t)(n0+r)*K + k0 + kb*8);
    }
    __syncthreads();
    bf16x8 af[4], bg[4];
    #pragma unroll
    for (int m=0;m<4;m++) af[m] = *(const bf16x8*)&Xs[(wr*64 + m*16 + lr)*40 + lk];
    #pragma unroll
    for (int n=0;n<4;n++) bg[n] = *(const bf16x8*)&Ws[(wc*64 + n*16 + lr)*40 + lk];
    #pragma unroll
    for (int m=0;m<4;m++)
      #pragma unroll
      for (int n=0;n<4;n++)
        acc[m][n] = __builtin_amdgcn_mfma_f32_16x16x32_bf16(af[m], bg[n], acc[m][n], 0, 0, 0);
  }
  float bsv[4];
  #pragma unroll
  for (int n=0;n<4;n++){
    int col = n0 + wc*64 + n*16 + lr;
    bsv[n] = ba[col] + (bb ? bb[col] : 0.f);
  }
  #pragma unroll
  for (int m=0;m<4;m++)
    #pragma unroll
    for (int n=0;n<4;n++)
      #pragma unroll
      for (int j=0;j<4;j++){
        int row = m0 + wr*64 + m*16 + (lane>>4)*4 + j;
        int col = n0 + wc*64 + n*16 + lr;
        out[(size_t)row*N + col] = acc[m][n][j] + bsv[n];
      }
}

// ---------------- K7: packed normalized attention output ----------------
__global__ __launch_bounds__(256) void k_attns(const float* __restrict__ A, const float* __restrict__ S,
    const int* __restrict__ pack_b, const int* __restrict__ pack_t, float* __restrict__ outA){
  int i = blockIdx.x;
  int b = pack_b[i], t = pack_t[i];
  float is = 1.f / S[b*64 + t];
  float4 v = ((const float4*)(A + ((size_t)(b*64+t))*NHW))[threadIdx.x];
  v.x*=is; v.y*=is; v.z*=is; v.w*=is;
  ((float4*)(outA + (size_t)i*NHW))[threadIdx.x] = v;
}

// ---------------- K3: BiLSTM scan via MFMA, 16 samples/block ----------------
// 16 blocks = 2 dirs x 8 sample-groups. Per step: G[16,512] = h[16,128] @ Whh^T (f16 MFMA,
// W streamed from shared global f16 copy, L2-resident). c-state in 4 regs/thread.
__global__ __launch_bounds__(512) void k_lstm_mfma(const float* __restrict__ Gf, const float* __restrict__ Gb,
    const f16_t* __restrict__ Whf, const f16_t* __restrict__ Whb, ushort_t* __restrict__ Clbf){
  int dir = blockIdx.x >> 3, b0 = (blockIdx.x & 7) * 16;
  const f16_t* W = dir ? Whb : Whf;      // [512][128]
  const float* G = dir ? Gb : Gf;        // [t][b][512]
  int tid = threadIdx.x, wave = tid>>6, lane = tid&63;
  int lr = lane & 15, lk = (lane>>4)*8;
  __shared__ f16_t hL[16*136];           // pitch 136 f16 (16B-aligned rows, bank-skewed)
  __shared__ float GL[16*520];           // pitch 520 f32
  for (int i=tid; i<16*136; i+=512) hL[i] = (f16_t)0.f;
  float c0s=0.f, c1s=0.f, c2s=0.f, c3s=0.f;
  __syncthreads();
  #pragma unroll 1
  for (int t=0;t<NTIME;t++){
    int tt = dir ? (NTIME-1-t) : t;
    // A-fragments from h (shared across this wave's 4 N-tiles)
    f16x8 af0 = *(const f16x8*)&hL[lr*136 + 0*32 + lk];
    f16x8 af1 = *(const f16x8*)&hL[lr*136 + 1*32 + lk];
    f16x8 af2 = *(const f16x8*)&hL[lr*136 + 2*32 + lk];
    f16x8 af3 = *(const f16x8*)&hL[lr*136 + 3*32 + lk];
    #pragma unroll
    for (int i=0;i<4;i++){
      int n0 = (wave*4 + i)*16;
      const f16_t* wrow = W + (size_t)(n0 + lr)*128;
      f32x4 acc = {0.f,0.f,0.f,0.f};
      acc = __builtin_amdgcn_mfma_f32_16x16x32_f16(af0, *(const f16x8*)(wrow + 0*32 + lk), acc, 0,0,0);
      acc = __builtin_amdgcn_mfma_f32_16x16x32_f16(af1, *(const f16x8*)(wrow + 1*32 + lk), acc, 0,0,0);
      acc = __builtin_amdgcn_mfma_f32_16x16x32_f16(af2, *(const f16x8*)(wrow + 2*32 + lk), acc, 0,0,0);
      acc = __builtin_amdgcn_mfma_f32_16x16x32_f16(af3, *(const f16x8*)(wrow + 3*32 + lk), acc, 0,0,0);
      #pragma unroll
      for (int j=0;j<4;j++) GL[((lane>>4)*4 + j)*520 + n0 + lr] = acc[j];
    }
    __syncthreads();
    // cell update: thread owns 4 outputs o = tid + k*512 -> s=o>>7, j=o&127
    #pragma unroll
    for (int k=0;k<4;k++){
      int o = tid + k*512, s = o>>7, j = o&127;
      const float* gg = G + ((size_t)tt*NBATCH + b0 + s)*512;
      float gi = sig_ (gg[j]       + GL[s*520 + j]);
      float gf = sig_ (gg[128 + j] + GL[s*520 + 128 + j]);
      float gc = tanh_(gg[256 + j] + GL[s*520 + 256 + j]);
      float go = sig_ (gg[384 + j] + GL[s*520 + 384 + j]);
      float cc = (k==0)?c0s:(k==1)?c1s:(k==2)?c2s:c3s;
      cc = gf*cc + gi*gc;
      float h = go*tanh_(cc);
      if (k==0) c0s=cc; else if (k==1) c1s=cc; else if (k==2) c2s=cc; else c3s=cc;
      hL[s*136 + j] = (f16_t)h;
      Clbf[((size_t)tt*NBATCH + b0 + s)*NCH + dir*128 + j] = f2bf(h);
    }
    __syncthreads();
  }
}

// ---------------- K4a: xs(bf16) = [Cl_bf | emb->bf16] ----------------
__global__ __launch_bounds__(256) void k_xs(const ushort_t* __restrict__ Clbf, const float* __restrict__ emb,
    const int* __restrict__ text, ushort_t* __restrict__ xsbf){
  int idx = blockIdx.x*256 + threadIdx.x;       // 8-elem chunks: 8192 rows x 64
  int row = idx>>6, c8 = idx&63;
  int t = row>>7, b = row&127;
  bf16x8 v;
  if (c8 < 32) v = *(const bf16x8*)(Clbf + (size_t)row*NCH + c8*8);
  else {
    int cls = (t==0) ? 0 : text[b*64 + (t-1)];
    const float4* e4 = (const float4*)(emb + (size_t)cls*NCH + (c8-32)*8);
    float4 a = e4[0], bq = e4[1];
    v[0]=(short)f2bf(a.x);  v[1]=(short)f2bf(a.y);  v[2]=(short)f2bf(a.z);  v[3]=(short)f2bf(a.w);
    v[4]=(short)f2bf(bq.x); v[5]=(short)f2bf(bq.y); v[6]=(short)f2bf(bq.z); v[7]=(short)f2bf(bq.w);
  }
  *(bf16x8*)(xsbf + (size_t)row*512 + c8*8) = v;
}

// ---------------- K5: GRU scan via MFMA, 16 samples/block ----------------
// 8 blocks. Per step: G[16,768] = h[16,256] @ Whh_g^T + bhh (f16 MFMA, W from shared
// global f16 copy). Then gate math, h -> LDS f16 + hsbf global.
__global__ __launch_bounds__(512) void k_gru_mfma(const float* __restrict__ gx,
    const f16_t* __restrict__ Whg, const float* __restrict__ bhh_g, ushort_t* __restrict__ hsbf){
  int b0 = blockIdx.x * 16;
  int tid = threadIdx.x, wave = tid>>6, lane = tid&63;
  int lr = lane & 15, lk = (lane>>4)*8;
  __shared__ f16_t hL[16*264];           // pitch 264 f16
  __shared__ float GL[16*776];           // pitch 776 f32
  __shared__ float bhhL[768];
  for (int i=tid; i<16*264; i+=512) hL[i] = (f16_t)0.f;
  for (int i=tid; i<768; i+=512) bhhL[i] = bhh_g[i];
  float hp0=0.f,hp1=0.f,hp2=0.f,hp3=0.f,hp4=0.f,hp5=0.f,hp6=0.f,hp7=0.f;
  __syncthreads();
  #pragma unroll 1
  for (int t=0;t<NTIME;t++){
    f16x8 af0 = *(const f16x8*)&hL[lr*264 + 0*32 + lk];
    f16x8 af1 = *(const f16x8*)&hL[lr*264 + 1*32 + lk];
    f16x8 af2 = *(const f16x8*)&hL[lr*264 + 2*32 + lk];
    f16x8 af3 = *(const f16x8*)&hL[lr*264 + 3*32 + lk];
    f16x8 af4 = *(const f16x8*)&hL[lr*264 + 4*32 + lk];
    f16x8 af5 = *(const f16x8*)&hL[lr*264 + 5*32 + lk];
    f16x8 af6 = *(const f16x8*)&hL[lr*264 + 6*32 + lk];
    f16x8 af7 = *(const f16x8*)&hL[lr*264 + 7*32 + lk];
    #pragma unroll
    for (int i=0;i<6;i++){
      int n0 = (wave*6 + i)*16;
      const f16_t* wrow = Whg + (size_t)(n0 + lr)*256;
      f32x4 acc = {0.f,0.f,0.f,0.f};
      acc = __builtin_amdgcn_mfma_f32_16x16x32_f16(af0, *(const f16x8*)(wrow + 0*32 + lk), acc, 0,0,0);
      acc = __builtin_amdgcn_mfma_f32_16x16x32_f16(af1, *(const f16x8*)(wrow + 1*32 + lk), acc, 0,0,0);
      acc = __builtin_amdgcn_mfma_f32_16x16x32_f16(af2, *(const f16x8*)(wrow + 2*32 + lk), acc, 0,0,0);
      acc = __builtin_amdgcn_mfma_f32_16x16x32_f16(af3, *(const f16x8*)(wrow + 3*32 + lk), acc, 0,0,0);
      acc = __builtin_amdgcn_mfma_f32_16x16x32_f16(af4, *(const f16x8*)(wrow + 4*32 + lk), acc, 0,0,0);
      acc = __builtin_amdgcn_mfma_f32_16x16x32_f16(af5, *(const f16x8*)(wrow + 5*32 + lk), acc, 0,0,0);
      acc = __builtin_amdgcn_mfma_f32_16x16x32_f16(af6, *(const f16x8*)(wrow + 6*32 + lk), acc, 0,0,0);
      acc = __builtin_amdgcn_mfma_f32_16x16x32_f16(af7, *(const f16x8*)(wrow + 7*32 + lk), acc, 0,0,0);
      float bb = bhhL[n0 + lr];
      #pragma unroll
      for (int j=0;j<4;j++) GL[((lane>>4)*4 + j)*776 + n0 + lr] = acc[j] + bb;
    }
    __syncthreads();
    // gate math: thread owns 8 outputs o = tid + k*512 -> s=o>>8, j=o&255
    #pragma unroll
    for (int k=0;k<8;k++){
      int o = tid + k*512, s = o>>8, j = o&255;
      const float* gxp = gx + ((size_t)t*NBATCH + b0 + s)*768;
      float r = sig_ (gxp[j]       + GL[s*776 + j]);
      float z = sig_ (gxp[256 + j] + GL[s*776 + 256 + j]);
      float n = tanh_(gxp[512 + j] + r*GL[s*776 + 512 + j]);
      float hp = (k==0)?hp0:(k==1)?hp1:(k==2)?hp2:(k==3)?hp3:(k==4)?hp4:(k==5)?hp5:(k==6)?hp6:hp7;
      float h = (1.f - z)*n + z*hp;
      if (k==0) hp0=h; else if (k==1) hp1=h; else if (k==2) hp2=h; else if (k==3) hp3=h;
      else if (k==4) hp4=h; else if (k==5) hp5=h; else if (k==6) hp6=h; else hp7=h;
      hL[s*264 + j] = (f16_t)h;
      hsbf[((size_t)t*NBATCH + b0 + s)*NCH + j] = f2bf(h);
    }
    __syncthreads();
  }
}

// ---------------- K6: logits via MFMA with row gather ----------------
__global__ __launch_bounds__(256) void k_logits_mfma(const ushort_t* __restrict__ hsbf,
    const int* __restrict__ pack_t, const int* __restrict__ pack_b,
    const ushort_t* __restrict__ Wbf, const float* __restrict__ bias,
    float* __restrict__ out, int L){
  __shared__ ushort_t Xs[64*40];
  __shared__ ushort_t Ws[128*40];
  __shared__ int rrow[64];
  int m0 = blockIdx.x*64;
  int tid = threadIdx.x, wave = tid>>6, lane = tid&63;
  int lr = lane & 15, lk = (lane>>4)*8;
  if (tid < 64){
    int m = m0 + tid;
    int pt = (m<L) ? pack_t[m] : 0;
    int pb = (m<L) ? pack_b[m] : 0;
    rrow[tid] = pt*NBATCH + pb;
  }
  f32x4 acc[4][2] = {};
  for (int k0=0;k0<NCH;k0+=32){
    __syncthreads();
    {
      int r = tid>>2, kb = tid&3;
      *(bf16x8*)&Xs[r*40 + kb*8] = *(const bf16x8*)(hsbf + (size_t)rrow[r]*NCH + k0 + kb*8);
    }
    #pragma unroll
    for (int i=0;i<2;i++){
      int c = tid + i*256, r = c>>2, kb = c&3;
      *(bf16x8*)&Ws[r*40 + kb*8] = *(const bf16x8*)(Wbf + (size_t)r*NCH + k0 + kb*8);
    }
    __syncthreads();
    bf16x8 af[4], bg[2];
    #pragma unroll
    for (int m=0;m<4;m++) af[m] = *(const bf16x8*)&Xs[(m*16 + lr)*40 + lk];
    #pragma unroll
    for (int n=0;n<2;n++) bg[n] = *(const bf16x8*)&Ws[(wave*32 + n*16 + lr)*40 + lk];
    #pragma unroll
    for (int m=0;m<4;m++)
      #pragma unroll
      for (int n=0;n<2;n++)
        acc[m][n] = __builtin_amdgcn_mfma_f32_16x16x32_bf16(af[m], bg[n], acc[m][n], 0, 0, 0);
  }
  #pragma unroll
  for (int m=0;m<4;m++)
    #pragma unroll
    for (int n=0;n<2;n++)
      #pragma unroll
      for (int j=0;j<4;j++){
        int row = m0 + m*16 + (lane>>4)*4 + j;
        int col = wave*32 + n*16 + lr;
        if (row < L) out[(size_t)row*NCLS + col] = acc[m][n][j] + bias[col];
      }
}

extern "C" void kernel_launch(void* const* d_in, const int* in_sizes, int n_in,
                              void* d_out, int out_size, void* d_ws, size_t ws_size,
                              hipStream_t stream) {
  const float* feature = (const float*)d_in[0];
  const float* A       = (const float*)d_in[1];
  const int*   text    = (const int*)d_in[2];
  const int*   pack_b  = (const int*)d_in[4];
  const int*   pack_t  = (const int*)d_in[5];
  const float* emb     = (const float*)d_in[6];
  const float* Wih_f   = (const float*)d_in[7];
  const float* Whh_f   = (const float*)d_in[8];
  const float* bih_f   = (const float*)d_in[9];
  const float* bhh_f   = (const float*)d_in[10];
  const float* Wih_b   = (const float*)d_in[11];
  const float* Whh_b   = (const float*)d_in[12];
  const float* bih_b   = (const float*)d_in[13];
  const float* bhh_b   = (const float*)d_in[14];
  const float* Wih_g   = (const float*)d_in[15];
  const float* Whh_g   = (const float*)d_in[16];
  const float* bih_g   = (const float*)d_in[17];
  const float* bhh_g   = (const float*)d_in[18];
  const float* Wgen    = (const float*)d_in[19];
  const float* bgen    = (const float*)d_in[20];
  int L = in_sizes[4];

  char* ws = (char*)d_ws;
  const size_t KB = 1024, MB = 1u<<20;
  float*    S       = (float*)(ws + 0);                    // 32 KB
  ushort_t* Wf_bf   = (ushort_t*)(ws + 1*MB);              // 256 KB
  ushort_t* Wb_bf   = (ushort_t*)(ws + 1*MB + 256*KB);     // 256 KB
  ushort_t* Wg_bf   = (ushort_t*)(ws + 1*MB + 512*KB);     // 768 KB
  ushort_t* Wgen_bf = (ushort_t*)(ws + 1*MB + 1280*KB);    // 64 KB
  f16_t*    Whf_h   = (f16_t*)(ws + 2*MB + 512*KB);        // 128 KB
  f16_t*    Whb_h   = (f16_t*)(ws + 2*MB + 640*KB);        // 128 KB
  f16_t*    Whg_h   = (f16_t*)(ws + 2*MB + 768*KB);        // 384 KB (ends 3.125MB)
  ushort_t* Cbf     = (ushort_t*)(ws + 4*MB);              // 4 MB  [t][b][256]
  ushort_t* Clbf    = (ushort_t*)(ws + 8*MB);              // 4 MB
  ushort_t* hsbf    = (ushort_t*)(ws + 12*MB);             // 4 MB
  float*    Gf      = (float*)(ws + 16*MB);                // 16 MB (dead after k_lstm)
  float*    Gb      = (float*)(ws + 32*MB);                // 16 MB (dead after k_lstm)
  ushort_t* xsbf    = (ushort_t*)(ws + 16*MB);             // 8 MB, aliases Gf
  float*    gx      = (float*)(ws + 24*MB);                // 25.2 MB, aliases Gb+

  float* out_res   = (float*)d_out;
  float* out_attns = out_res + (size_t)L*NCLS;

  k_convw<<<512, 256, 0, stream>>>(Wih_f, Wf_bf, 512*256);
  k_convw<<<512, 256, 0, stream>>>(Wih_b, Wb_bf, 512*256);
  k_convw<<<1536, 256, 0, stream>>>(Wih_g, Wg_bf, 768*512);
  k_convw<<<128, 256, 0, stream>>>(Wgen, Wgen_bf, 128*256);
  k_convh<<<256, 256, 0, stream>>>(Whh_f, Whf_h, 512*128);
  k_convh<<<256, 256, 0, stream>>>(Whh_b, Whb_h, 512*128);
  k_convh<<<768, 256, 0, stream>>>(Whh_g, Whg_h, 768*256);
  k_rowsum<<<8192, 256, 0, stream>>>(A, S);
  k_pool_mfma<<<256, 256, 0, stream>>>(feature, A, S, Cbf);
  k_attns<<<L, 256, 0, stream>>>(A, S, pack_b, pack_t, out_attns);
  k_gemm_bf<<<dim3(4,64), 256, 0, stream>>>(Cbf, Wf_bf, bih_f, bhh_f, Gf, 512, 256);
  k_gemm_bf<<<dim3(4,64), 256, 0, stream>>>(Cbf, Wb_bf, bih_b, bhh_b, Gb, 512, 256);
  k_lstm_mfma<<<16, 512, 0, stream>>>(Gf, Gb, Whf_h, Whb_h, Clbf);
  k_xs<<<2048, 256, 0, stream>>>(Clbf, emb, text, xsbf);
  k_gemm_bf<<<dim3(6,64), 256, 0, stream>>>(xsbf, Wg_bf, bih_g, nullptr, gx, 768, 512);
  k_gru_mfma<<<8, 512, 0, stream>>>(gx, Whg_h, bhh_g, hsbf);
  k_logits_mfma<<<(L+63)/64, 256, 0, stream>>>(hsbf, pack_t, pack_b, Wgen_bf, bgen, out_res, L);
}

// Round 13
// 456.112 us; speedup vs baseline: 2.0394x; 2.0394x over previous
//
#include <hip/hip_runtime.h>
#include <cstdint>
#include <cstddef>

#define NBATCH 128
#define NCH    256
#define NHW    1024
#define NTIME  64
#define NCLS   128

typedef _Float16 f16_t;
typedef _Float16 f16x8 __attribute__((ext_vector_type(8)));
typedef _Float16 half2_t __attribute__((ext_vector_type(2)));
typedef short bf16x8 __attribute__((ext_vector_type(8)));
typedef short bf16x4 __attribute__((ext_vector_type(4)));
typedef float f32x4 __attribute__((ext_vector_type(4)));
typedef unsigned short ushort_t;

#if defined(__has_builtin)
#  if __has_builtin(__builtin_amdgcn_fdot2)
#    define HAS_FDOT2 1
#  endif
#endif
#ifndef HAS_FDOT2
#  define HAS_FDOT2 0
#endif

__device__ __forceinline__ float dot2acc(half2_t a, half2_t b, float c){
#if HAS_FDOT2
  return __builtin_amdgcn_fdot2(a, b, c, false);
#else
  return c + (float)a.x*(float)b.x + (float)a.y*(float)b.y;
#endif
}
__device__ __forceinline__ half2_t pack2(float x, float y){
  half2_t p; p.x = (_Float16)x; p.y = (_Float16)y; return p;
}
__device__ __forceinline__ ushort_t f2bf(float x){
  unsigned u = __builtin_bit_cast(unsigned, x);
  unsigned r = (u + 0x7FFFu + ((u>>16)&1u)) >> 16;
  return (ushort_t)r;
}
__device__ __forceinline__ float sig_(float x){
  x = fminf(30.f, fmaxf(-30.f, x));
  return 1.f/(1.f+__expf(-x));
}
__device__ __forceinline__ float tanh_(float x){
  x = fminf(15.f, fmaxf(-15.f, x));
  float e = __expf(2.f*x);
  return (e-1.f)/(e+1.f);
}

// ---------------- K0: row sums of A -> S[b*64+t] ----------------
__global__ __launch_bounds__(256) void k_rowsum(const float* __restrict__ A, float* __restrict__ S){
  int row = blockIdx.x;
  const float4* a4 = (const float4*)(A + (size_t)row*NHW);
  float4 v = a4[threadIdx.x];
  float s = v.x+v.y+v.z+v.w;
  #pragma unroll
  for (int off=32; off>0; off>>=1) s += __shfl_down(s, off, 64);
  __shared__ float wsum[4];
  int lane = threadIdx.x & 63, w = threadIdx.x >> 6;
  if (lane==0) wsum[w] = s;
  __syncthreads();
  if (threadIdx.x==0) S[row] = wsum[0]+wsum[1]+wsum[2]+wsum[3];
}

// ---------------- weight converts ----------------
__global__ __launch_bounds__(256) void k_convw(const float* __restrict__ src, ushort_t* __restrict__ dst, int n){
  int i = blockIdx.x*256 + threadIdx.x;
  if (i < n) dst[i] = f2bf(src[i]);
}
__global__ __launch_bounds__(256) void k_convh(const float* __restrict__ src, f16_t* __restrict__ dst, int n){
  int i = blockIdx.x*256 + threadIdx.x;
  if (i < n) dst[i] = (f16_t)src[i];
}

// ---------------- K1: attention pooling via MFMA ----------------
__global__ __launch_bounds__(256) void k_pool_mfma(const float* __restrict__ feat, const float* __restrict__ A,
    const float* __restrict__ S, ushort_t* __restrict__ Cbf){
  __shared__ ushort_t As_[64*40];
  __shared__ ushort_t Fs_[128*40];
  __shared__ float sinvs[64];
  int b = blockIdx.x >> 1, ch = blockIdx.x & 1, c0 = ch*128;
  int tid = threadIdx.x, wave = tid>>6, lane = tid&63;
  if (tid < 64) sinvs[tid] = 1.f / S[b*64 + tid];
  f32x4 acc[4][2] = {};
  int lr = lane & 15, lk = (lane>>4)*8;
  for (int k0=0;k0<NHW;k0+=32){
    __syncthreads();
    #pragma unroll
    for (int i=0;i<2;i++){
      int c = tid + i*256, r = c>>3, kq = c&7;
      float4 v = *(const float4*)(A + ((size_t)(b*64+r))*NHW + k0 + kq*4);
      bf16x4 p; p[0]=(short)f2bf(v.x); p[1]=(short)f2bf(v.y); p[2]=(short)f2bf(v.z); p[3]=(short)f2bf(v.w);
      *(bf16x4*)&As_[r*40 + kq*4] = p;
    }
    #pragma unroll
    for (int i=0;i<4;i++){
      int c = tid + i*256, r = c>>3, kq = c&7;
      float4 v = *(const float4*)(feat + ((size_t)(b*256+c0+r))*NHW + k0 + kq*4);
      bf16x4 p; p[0]=(short)f2bf(v.x); p[1]=(short)f2bf(v.y); p[2]=(short)f2bf(v.z); p[3]=(short)f2bf(v.w);
      *(bf16x4*)&Fs_[r*40 + kq*4] = p;
    }
    __syncthreads();
    bf16x8 af[4], bg[2];
    #pragma unroll
    for (int m=0;m<4;m++) af[m] = *(const bf16x8*)&As_[(m*16 + lr)*40 + lk];
    #pragma unroll
    for (int n=0;n<2;n++) bg[n] = *(const bf16x8*)&Fs_[(wave*32 + n*16 + lr)*40 + lk];
    #pragma unroll
    for (int m=0;m<4;m++)
      #pragma unroll
      for (int n=0;n<2;n++)
        acc[m][n] = __builtin_amdgcn_mfma_f32_16x16x32_bf16(af[m], bg[n], acc[m][n], 0, 0, 0);
  }
  #pragma unroll
  for (int m=0;m<4;m++)
    #pragma unroll
    for (int n=0;n<2;n++)
      #pragma unroll
      for (int j=0;j<4;j++){
        int t = m*16 + (lane>>4)*4 + j;
        int c = c0 + wave*32 + n*16 + lr;
        Cbf[((size_t)t*NBATCH + b)*NCH + c] = f2bf(acc[m][n][j] * sinvs[t]);
      }
}

// ---------------- generic bf16 MFMA GEMM: out[M][N]fp32 = Xbf[M][K] @ Wbf[N][K]^T + ba(+bb) ---
__global__ __launch_bounds__(256) void k_gemm_bf(const ushort_t* __restrict__ X, const ushort_t* __restrict__ W,
    const float* __restrict__ ba, const float* __restrict__ bb, float* __restrict__ out, int N, int K){
  __shared__ ushort_t Xs[128*40];
  __shared__ ushort_t Ws[128*40];
  int n0 = blockIdx.x*128, m0 = blockIdx.y*128;
  int tid = threadIdx.x, wave = tid>>6, lane = tid&63;
  int wr = wave>>1, wc = wave&1;
  int lr = lane & 15, lk = (lane>>4)*8;
  f32x4 acc[4][4] = {};
  for (int k0=0;k0<K;k0+=32){
    __syncthreads();
    #pragma unroll
    for (int i=0;i<2;i++){
      int c = tid + i*256, r = c>>2, kb = c&3;
      *(bf16x8*)&Xs[r*40 + kb*8] = *(const bf16x8*)(X + (size_t)(m0+r)*K + k0 + kb*8);
      *(bf16x8*)&Ws[r*40 + kb*8] = *(const bf16x8*)(W + (size_t)(n0+r)*K + k0 + kb*8);
    }
    __syncthreads();
    bf16x8 af[4], bg[4];
    #pragma unroll
    for (int m=0;m<4;m++) af[m] = *(const bf16x8*)&Xs[(wr*64 + m*16 + lr)*40 + lk];
    #pragma unroll
    for (int n=0;n<4;n++) bg[n] = *(const bf16x8*)&Ws[(wc*64 + n*16 + lr)*40 + lk];
    #pragma unroll
    for (int m=0;m<4;m++)
      #pragma unroll
      for (int n=0;n<4;n++)
        acc[m][n] = __builtin_amdgcn_mfma_f32_16x16x32_bf16(af[m], bg[n], acc[m][n], 0, 0, 0);
  }
  float bsv[4];
  #pragma unroll
  for (int n=0;n<4;n++){
    int col = n0 + wc*64 + n*16 + lr;
    bsv[n] = ba[col] + (bb ? bb[col] : 0.f);
  }
  #pragma unroll
  for (int m=0;m<4;m++)
    #pragma unroll
    for (int n=0;n<4;n++)
      #pragma unroll
      for (int j=0;j<4;j++){
        int row = m0 + wr*64 + m*16 + (lane>>4)*4 + j;
        int col = n0 + wc*64 + n*16 + lr;
        out[(size_t)row*N + col] = acc[m][n][j] + bsv[n];
      }
}

// ---------------- K7: packed normalized attention output ----------------
__global__ __launch_bounds__(256) void k_attns(const float* __restrict__ A, const float* __restrict__ S,
    const int* __restrict__ pack_b, const int* __restrict__ pack_t, float* __restrict__ outA){
  int i = blockIdx.x;
  int b = pack_b[i], t = pack_t[i];
  float is = 1.f / S[b*64 + t];
  float4 v = ((const float4*)(A + ((size_t)(b*64+t))*NHW))[threadIdx.x];
  v.x*=is; v.y*=is; v.z*=is; v.w*=is;
  ((float4*)(outA + (size_t)i*NHW))[threadIdx.x] = v;
}

// ---------------- K3: BiLSTM scan via MFMA, W resident in LDS (139KB) ----------------
// 32 blocks = 2 dirs x 16 groups x 8 samples. W loaded ONCE into LDS; 64 steps pure
// LDS-MFMA. Dynamic LDS: Wl[512*136]f16 + GL[8*520]f32 + hL[16*136]f16 = 160,256 B.
__global__ __launch_bounds__(512) void k_lstm_lds(const float* __restrict__ Gf, const float* __restrict__ Gb,
    const f16_t* __restrict__ Whf, const f16_t* __restrict__ Whb, ushort_t* __restrict__ Clbf){
  extern __shared__ char smem[];
  f16_t* Wl = (f16_t*)smem;                       // [512][136]
  float* GL = (float*)(smem + 512*136*2);         // [8][520]
  f16_t* hL = (f16_t*)(smem + 512*136*2 + 8*520*4); // [16][136]
  int dir = blockIdx.x >> 4, b0 = (blockIdx.x & 15) * 8;
  const f16_t* W = dir ? Whb : Whf;               // [512][128]
  const float* G = dir ? Gb : Gf;                 // [t][128][512] (biases folded)
  int tid = threadIdx.x, wave = tid>>6, lane = tid&63;
  int lr = lane & 15, lk = (lane>>4)*8;
  // load W once (512 rows x 16 f16x8 chunks)
  for (int i=tid; i<512*16; i+=512){
    int r = i>>4, c = i&15;
    *(f16x8*)&Wl[r*136 + c*8] = *(const f16x8*)(W + (size_t)r*128 + c*8);
  }
  for (int i=tid; i<16*136; i+=512) hL[i] = (f16_t)0.f;
  float c0s = 0.f, c1s = 0.f;
  __syncthreads();
  #pragma unroll 1
  for (int t=0;t<NTIME;t++){
    int tt = dir ? (NTIME-1-t) : t;
    // A-fragments from h (rows 8..15 stay zero)
    f16x8 af0 = *(const f16x8*)&hL[lr*136 + 0*32 + lk];
    f16x8 af1 = *(const f16x8*)&hL[lr*136 + 1*32 + lk];
    f16x8 af2 = *(const f16x8*)&hL[lr*136 + 2*32 + lk];
    f16x8 af3 = *(const f16x8*)&hL[lr*136 + 3*32 + lk];
    #pragma unroll
    for (int i=0;i<4;i++){
      int n0 = (wave*4 + i)*16;
      const f16_t* wrow = Wl + (size_t)(n0 + lr)*136;
      f32x4 acc = {0.f,0.f,0.f,0.f};
      acc = __builtin_amdgcn_mfma_f32_16x16x32_f16(af0, *(const f16x8*)(wrow + 0*32 + lk), acc, 0,0,0);
      acc = __builtin_amdgcn_mfma_f32_16x16x32_f16(af1, *(const f16x8*)(wrow + 1*32 + lk), acc, 0,0,0);
      acc = __builtin_amdgcn_mfma_f32_16x16x32_f16(af2, *(const f16x8*)(wrow + 2*32 + lk), acc, 0,0,0);
      acc = __builtin_amdgcn_mfma_f32_16x16x32_f16(af3, *(const f16x8*)(wrow + 3*32 + lk), acc, 0,0,0);
      #pragma unroll
      for (int j=0;j<4;j++){
        int gr = (lane>>4)*4 + j;
        if (gr < 8) GL[gr*520 + n0 + lr] = acc[j];
      }
    }
    __syncthreads();
    // cell update: thread owns 2 outputs o = tid + k*512 -> s=o>>7, j=o&127
    #pragma unroll
    for (int k=0;k<2;k++){
      int o = tid + k*512, s = o>>7, j = o&127;
      const float* gg = G + ((size_t)tt*NBATCH + b0 + s)*512;
      float gi = sig_ (gg[j]       + GL[s*520 + j]);
      float gf = sig_ (gg[128 + j] + GL[s*520 + 128 + j]);
      float gc = tanh_(gg[256 + j] + GL[s*520 + 256 + j]);
      float go = sig_ (gg[384 + j] + GL[s*520 + 384 + j]);
      float cc = (k==0) ? c0s : c1s;
      cc = gf*cc + gi*gc;
      float h = go*tanh_(cc);
      if (k==0) c0s=cc; else c1s=cc;
      hL[s*136 + j] = (f16_t)h;
      Clbf[((size_t)tt*NBATCH + b0 + s)*NCH + dir*128 + j] = f2bf(h);
    }
    __syncthreads();
  }
}

// ---------------- K4a: xs(bf16) = [Cl_bf | emb->bf16] ----------------
__global__ __launch_bounds__(256) void k_xs(const ushort_t* __restrict__ Clbf, const float* __restrict__ emb,
    const int* __restrict__ text, ushort_t* __restrict__ xsbf){
  int idx = blockIdx.x*256 + threadIdx.x;       // 8-elem chunks: 8192 rows x 64
  int row = idx>>6, c8 = idx&63;
  int t = row>>7, b = row&127;
  bf16x8 v;
  if (c8 < 32) v = *(const bf16x8*)(Clbf + (size_t)row*NCH + c8*8);
  else {
    int cls = (t==0) ? 0 : text[b*64 + (t-1)];
    const float4* e4 = (const float4*)(emb + (size_t)cls*NCH + (c8-32)*8);
    float4 a = e4[0], bq = e4[1];
    v[0]=(short)f2bf(a.x);  v[1]=(short)f2bf(a.y);  v[2]=(short)f2bf(a.z);  v[3]=(short)f2bf(a.w);
    v[4]=(short)f2bf(bq.x); v[5]=(short)f2bf(bq.y); v[6]=(short)f2bf(bq.z); v[7]=(short)f2bf(bq.w);
  }
  *(bf16x8*)(xsbf + (size_t)row*512 + c8*8) = v;
}

// ---------------- K5: GRU scan (R8/R9-measured 151us version) ----------------
// 512 threads, (512,1). 1536 tasks = 768 rows x 2 k-halves; 3 tasks/thread.
__global__ __launch_bounds__(512, 1) void k_gru(const float* __restrict__ gx,
    const float* __restrict__ Whh_g, const float* __restrict__ bhh_g, ushort_t* __restrict__ hsbf){
  int b = blockIdx.x, t0 = threadIdx.x, lane = t0 & 63, w = t0 >> 6;
  half2_t wpA[64], wpB[64], wpC[64];
  int pidxA, pidxB, pidxC;
  int hfbA, hfbB, hfbC;

#define LOADW(WP, PIDX, HFB, S) do { \
    int c = w*3 + (S); \
    int hf = (c >= 12) ? 1 : 0; \
    int row = (c - hf*12)*64 + lane; \
    PIDX = hf*768 + row; \
    HFB  = __builtin_amdgcn_readfirstlane(hf*32); \
    const float4* wr = (const float4*)(Whh_g + (size_t)row*256 + hf*128); \
    _Pragma("unroll") \
    for (int j=0;j<32;j++){ \
      float4 v = wr[j]; \
      WP[2*j]   = pack2(v.x, v.y); \
      WP[2*j+1] = pack2(v.z, v.w); \
    } \
  } while(0)

  LOADW(wpA, pidxA, hfbA, 0);
  LOADW(wpB, pidxB, hfbB, 1);
  LOADW(wpC, pidxC, hfbC, 2);
#undef LOADW

  __shared__ float h32[256];
  __shared__ float partLds[1536];
  __shared__ float bhL[768];
  if (t0 < 256) h32[t0] = 0.f;
  bhL[t0] = bhh_g[t0];
  if (t0 < 256) bhL[512+t0] = bhh_g[512+t0];
  float hprev = 0.f;
  __syncthreads();
  #pragma unroll 1
  for (int t=0;t<NTIME;t++){
    float gxr=0.f, gxz=0.f, gxn=0.f;
    if (t0 < 256){
      const float* gxp = gx + ((size_t)t*NBATCH + b)*768;
      gxr = gxp[t0]; gxz = gxp[256+t0]; gxn = gxp[512+t0];
    }
    float4 hq = *(const float4*)(h32 + 4*lane);
    int hpk0 = __builtin_bit_cast(int, pack2(hq.x, hq.y));
    int hpk1 = __builtin_bit_cast(int, pack2(hq.z, hq.w));

#define DOTASK(WP, PIDX, HFB) do { \
    float a0=0.f, a1=0.f, a2=0.f, a3=0.f; \
    _Pragma("unroll") \
    for (int jj=0;jj<64;jj+=2){ \
      int hv0 = __builtin_amdgcn_readlane(hpk0, HFB + (jj>>1)); \
      int hv1 = __builtin_amdgcn_readlane(hpk1, HFB + (jj>>1)); \
      if ((jj>>1)&1){ \
        a2 = dot2acc(WP[jj],   __builtin_bit_cast(half2_t, hv0), a2); \
        a3 = dot2acc(WP[jj+1], __builtin_bit_cast(half2_t, hv1), a3); \
      } else { \
        a0 = dot2acc(WP[jj],   __builtin_bit_cast(half2_t, hv0), a0); \
        a1 = dot2acc(WP[jj+1], __builtin_bit_cast(half2_t, hv1), a1); \
      } \
    } \
    partLds[PIDX] = a0+a1+a2+a3; \
  } while(0)

    DOTASK(wpA, pidxA, hfbA);
    DOTASK(wpB, pidxB, hfbB);
    DOTASK(wpC, pidxC, hfbC);
#undef DOTASK

    __syncthreads();
    if (t0 < 256){
      float rh = bhL[t0]     + partLds[t0]     + partLds[768+t0];
      float zh = bhL[256+t0] + partLds[256+t0] + partLds[1024+t0];
      float nh = bhL[512+t0] + partLds[512+t0] + partLds[1280+t0];
      float r = sig_(gxr + rh);
      float z = sig_(gxz + zh);
      float n = tanh_(gxn + r*nh);
      float h = (1.f-z)*n + z*hprev;
      hprev = h;
      h32[t0] = h;
      hsbf[((size_t)t*NBATCH + b)*NCH + t0] = f2bf(h);
    }
    __syncthreads();
  }
}

// ---------------- K6: logits via MFMA with row gather ----------------
__global__ __launch_bounds__(256) void k_logits_mfma(const ushort_t* __restrict__ hsbf,
    const int* __restrict__ pack_t, const int* __restrict__ pack_b,
    const ushort_t* __restrict__ Wbf, const float* __restrict__ bias,
    float* __restrict__ out, int L){
  __shared__ ushort_t Xs[64*40];
  __shared__ ushort_t Ws[128*40];
  __shared__ int rrow[64];
  int m0 = blockIdx.x*64;
  int tid = threadIdx.x, wave = tid>>6, lane = tid&63;
  int lr = lane & 15, lk = (lane>>4)*8;
  if (tid < 64){
    int m = m0 + tid;
    int pt = (m<L) ? pack_t[m] : 0;
    int pb = (m<L) ? pack_b[m] : 0;
    rrow[tid] = pt*NBATCH + pb;
  }
  f32x4 acc[4][2] = {};
  for (int k0=0;k0<NCH;k0+=32){
    __syncthreads();
    {
      int r = tid>>2, kb = tid&3;
      *(bf16x8*)&Xs[r*40 + kb*8] = *(const bf16x8*)(hsbf + (size_t)rrow[r]*NCH + k0 + kb*8);
    }
    #pragma unroll
    for (int i=0;i<2;i++){
      int c = tid + i*256, r = c>>2, kb = c&3;
      *(bf16x8*)&Ws[r*40 + kb*8] = *(const bf16x8*)(Wbf + (size_t)r*NCH + k0 + kb*8);
    }
    __syncthreads();
    bf16x8 af[4], bg[2];
    #pragma unroll
    for (int m=0;m<4;m++) af[m] = *(const bf16x8*)&Xs[(m*16 + lr)*40 + lk];
    #pragma unroll
    for (int n=0;n<2;n++) bg[n] = *(const bf16x8*)&Ws[(wave*32 + n*16 + lr)*40 + lk];
    #pragma unroll
    for (int m=0;m<4;m++)
      #pragma unroll
      for (int n=0;n<2;n++)
        acc[m][n] = __builtin_amdgcn_mfma_f32_16x16x32_bf16(af[m], bg[n], acc[m][n], 0, 0, 0);
  }
  #pragma unroll
  for (int m=0;m<4;m++)
    #pragma unroll
    for (int n=0;n<2;n++)
      #pragma unroll
      for (int j=0;j<4;j++){
        int row = m0 + m*16 + (lane>>4)*4 + j;
        int col = wave*32 + n*16 + lr;
        if (row < L) out[(size_t)row*NCLS + col] = acc[m][n][j] + bias[col];
      }
}

extern "C" void kernel_launch(void* const* d_in, const int* in_sizes, int n_in,
                              void* d_out, int out_size, void* d_ws, size_t ws_size,
                              hipStream_t stream) {
  const float* feature = (const float*)d_in[0];
  const float* A       = (const float*)d_in[1];
  const int*   text    = (const int*)d_in[2];
  const int*   pack_b  = (const int*)d_in[4];
  const int*   pack_t  = (const int*)d_in[5];
  const float* emb     = (const float*)d_in[6];
  const float* Wih_f   = (const float*)d_in[7];
  const float* Whh_f   = (const float*)d_in[8];
  const float* bih_f   = (const float*)d_in[9];
  const float* bhh_f   = (const float*)d_in[10];
  const float* Wih_b   = (const float*)d_in[11];
  const float* Whh_b   = (const float*)d_in[12];
  const float* bih_b   = (const float*)d_in[13];
  const float* bhh_b   = (const float*)d_in[14];
  const float* Wih_g   = (const float*)d_in[15];
  const float* Whh_g   = (const float*)d_in[16];
  const float* bih_g   = (const float*)d_in[17];
  const float* bhh_g   = (const float*)d_in[18];
  const float* Wgen    = (const float*)d_in[19];
  const float* bgen    = (const float*)d_in[20];
  int L = in_sizes[4];

  char* ws = (char*)d_ws;
  const size_t KB = 1024, MB = 1u<<20;
  float*    S       = (float*)(ws + 0);                    // 32 KB
  ushort_t* Wf_bf   = (ushort_t*)(ws + 1*MB);              // 256 KB
  ushort_t* Wb_bf   = (ushort_t*)(ws + 1*MB + 256*KB);     // 256 KB
  ushort_t* Wg_bf   = (ushort_t*)(ws + 1*MB + 512*KB);     // 768 KB
  ushort_t* Wgen_bf = (ushort_t*)(ws + 1*MB + 1280*KB);    // 64 KB
  f16_t*    Whf_h   = (f16_t*)(ws + 2*MB + 512*KB);        // 128 KB
  f16_t*    Whb_h   = (f16_t*)(ws + 2*MB + 640*KB);        // 128 KB
  ushort_t* Cbf     = (ushort_t*)(ws + 4*MB);              // 4 MB  [t][b][256]
  ushort_t* Clbf    = (ushort_t*)(ws + 8*MB);              // 4 MB
  ushort_t* hsbf    = (ushort_t*)(ws + 12*MB);             // 4 MB
  float*    Gf      = (float*)(ws + 16*MB);                // 16 MB (dead after k_lstm)
  float*    Gb      = (float*)(ws + 32*MB);                // 16 MB (dead after k_lstm)
  ushort_t* xsbf    = (ushort_t*)(ws + 16*MB);             // 8 MB, aliases Gf
  float*    gx      = (float*)(ws + 24*MB);                // 25.2 MB, aliases Gb+

  float* out_res   = (float*)d_out;
  float* out_attns = out_res + (size_t)L*NCLS;

  const int LSTM_SMEM = 512*136*2 + 8*520*4 + 16*136*2;    // 160,256 B
  (void)hipFuncSetAttribute((const void*)k_lstm_lds,
                            hipFuncAttributeMaxDynamicSharedMemorySize, LSTM_SMEM);

  k_convw<<<512, 256, 0, stream>>>(Wih_f, Wf_bf, 512*256);
  k_convw<<<512, 256, 0, stream>>>(Wih_b, Wb_bf, 512*256);
  k_convw<<<1536, 256, 0, stream>>>(Wih_g, Wg_bf, 768*512);
  k_convw<<<128, 256, 0, stream>>>(Wgen, Wgen_bf, 128*256);
  k_convh<<<256, 256, 0, stream>>>(Whh_f, Whf_h, 512*128);
  k_convh<<<256, 256, 0, stream>>>(Whh_b, Whb_h, 512*128);
  k_rowsum<<<8192, 256, 0, stream>>>(A, S);
  k_pool_mfma<<<256, 256, 0, stream>>>(feature, A, S, Cbf);
  k_attns<<<L, 256, 0, stream>>>(A, S, pack_b, pack_t, out_attns);
  k_gemm_bf<<<dim3(4,64), 256, 0, stream>>>(Cbf, Wf_bf, bih_f, bhh_f, Gf, 512, 256);
  k_gemm_bf<<<dim3(4,64), 256, 0, stream>>>(Cbf, Wb_bf, bih_b, bhh_b, Gb, 512, 256);
  k_lstm_lds<<<32, 512, LSTM_SMEM, stream>>>(Gf, Gb, Whf_h, Whb_h, Clbf);
  k_xs<<<2048, 256, 0, stream>>>(Clbf, emb, text, xsbf);
  k_gemm_bf<<<dim3(6,64), 256, 0, stream>>>(xsbf, Wg_bf, bih_g, nullptr, gx, 768, 512);
  k_gru<<<128, 512, 0, stream>>>(gx, Whh_g, bhh_g, hsbf);
  k_logits_mfma<<<(L+63)/64, 256, 0, stream>>>(hsbf, pack_t, pack_b, Wgen_bf, bgen, out_res, L);
}

// Round 14
// 403.800 us; speedup vs baseline: 2.3036x; 1.1295x over previous
//
#include <hip/hip_runtime.h>
#include <cstdint>
#include <cstddef>

#define NBATCH 128
#define NCH    256
#define NHW    1024
#define NTIME  64
#define NCLS   128

typedef _Float16 f16_t;
typedef _Float16 f16x8 __attribute__((ext_vector_type(8)));
typedef _Float16 half2_t __attribute__((ext_vector_type(2)));
typedef short bf16x8 __attribute__((ext_vector_type(8)));
typedef short bf16x4 __attribute__((ext_vector_type(4)));
typedef float f32x4 __attribute__((ext_vector_type(4)));
typedef unsigned short ushort_t;

#if defined(__has_builtin)
#  if __has_builtin(__builtin_amdgcn_fdot2)
#    define HAS_FDOT2 1
#  endif
#endif
#ifndef HAS_FDOT2
#  define HAS_FDOT2 0
#endif

__device__ __forceinline__ float dot2acc(half2_t a, half2_t b, float c){
#if HAS_FDOT2
  return __builtin_amdgcn_fdot2(a, b, c, false);
#else
  return c + (float)a.x*(float)b.x + (float)a.y*(float)b.y;
#endif
}
__device__ __forceinline__ half2_t pack2(float x, float y){
  half2_t p; p.x = (_Float16)x; p.y = (_Float16)y; return p;
}
#define BCH(x) __builtin_bit_cast(half2_t, (x))
__device__ __forceinline__ ushort_t f2bf(float x){
  unsigned u = __builtin_bit_cast(unsigned, x);
  unsigned r = (u + 0x7FFFu + ((u>>16)&1u)) >> 16;
  return (ushort_t)r;
}
__device__ __forceinline__ float sig_(float x){
  x = fminf(30.f, fmaxf(-30.f, x));
  return 1.f/(1.f+__expf(-x));
}
__device__ __forceinline__ float tanh_(float x){
  x = fminf(15.f, fmaxf(-15.f, x));
  float e = __expf(2.f*x);
  return (e-1.f)/(e+1.f);
}

// ---------------- K0: row sums of A -> S[b*64+t] ----------------
__global__ __launch_bounds__(256) void k_rowsum(const float* __restrict__ A, float* __restrict__ S){
  int row = blockIdx.x;
  const float4* a4 = (const float4*)(A + (size_t)row*NHW);
  float4 v = a4[threadIdx.x];
  float s = v.x+v.y+v.z+v.w;
  #pragma unroll
  for (int off=32; off>0; off>>=1) s += __shfl_down(s, off, 64);
  __shared__ float wsum[4];
  int lane = threadIdx.x & 63, w = threadIdx.x >> 6;
  if (lane==0) wsum[w] = s;
  __syncthreads();
  if (threadIdx.x==0) S[row] = wsum[0]+wsum[1]+wsum[2]+wsum[3];
}

// ---------------- weight converts ----------------
__global__ __launch_bounds__(256) void k_convw(const float* __restrict__ src, ushort_t* __restrict__ dst, int n){
  int i = blockIdx.x*256 + threadIdx.x;
  if (i < n) dst[i] = f2bf(src[i]);
}
__global__ __launch_bounds__(256) void k_convh(const float* __restrict__ src, f16_t* __restrict__ dst, int n){
  int i = blockIdx.x*256 + threadIdx.x;
  if (i < n) dst[i] = (f16_t)src[i];
}

// ---------------- K1: attention pooling via MFMA ----------------
__global__ __launch_bounds__(256) void k_pool_mfma(const float* __restrict__ feat, const float* __restrict__ A,
    const float* __restrict__ S, ushort_t* __restrict__ Cbf){
  __shared__ ushort_t As_[64*40];
  __shared__ ushort_t Fs_[128*40];
  __shared__ float sinvs[64];
  int b = blockIdx.x >> 1, ch = blockIdx.x & 1, c0 = ch*128;
  int tid = threadIdx.x, wave = tid>>6, lane = tid&63;
  if (tid < 64) sinvs[tid] = 1.f / S[b*64 + tid];
  f32x4 acc[4][2] = {};
  int lr = lane & 15, lk = (lane>>4)*8;
  for (int k0=0;k0<NHW;k0+=32){
    __syncthreads();
    #pragma unroll
    for (int i=0;i<2;i++){
      int c = tid + i*256, r = c>>3, kq = c&7;
      float4 v = *(const float4*)(A + ((size_t)(b*64+r))*NHW + k0 + kq*4);
      bf16x4 p; p[0]=(short)f2bf(v.x); p[1]=(short)f2bf(v.y); p[2]=(short)f2bf(v.z); p[3]=(short)f2bf(v.w);
      *(bf16x4*)&As_[r*40 + kq*4] = p;
    }
    #pragma unroll
    for (int i=0;i<4;i++){
      int c = tid + i*256, r = c>>3, kq = c&7;
      float4 v = *(const float4*)(feat + ((size_t)(b*256+c0+r))*NHW + k0 + kq*4);
      bf16x4 p; p[0]=(short)f2bf(v.x); p[1]=(short)f2bf(v.y); p[2]=(short)f2bf(v.z); p[3]=(short)f2bf(v.w);
      *(bf16x4*)&Fs_[r*40 + kq*4] = p;
    }
    __syncthreads();
    bf16x8 af[4], bg[2];
    #pragma unroll
    for (int m=0;m<4;m++) af[m] = *(const bf16x8*)&As_[(m*16 + lr)*40 + lk];
    #pragma unroll
    for (int n=0;n<2;n++) bg[n] = *(const bf16x8*)&Fs_[(wave*32 + n*16 + lr)*40 + lk];
    #pragma unroll
    for (int m=0;m<4;m++)
      #pragma unroll
      for (int n=0;n<2;n++)
        acc[m][n] = __builtin_amdgcn_mfma_f32_16x16x32_bf16(af[m], bg[n], acc[m][n], 0, 0, 0);
  }
  #pragma unroll
  for (int m=0;m<4;m++)
    #pragma unroll
    for (int n=0;n<2;n++)
      #pragma unroll
      for (int j=0;j<4;j++){
        int t = m*16 + (lane>>4)*4 + j;
        int c = c0 + wave*32 + n*16 + lr;
        Cbf[((size_t)t*NBATCH + b)*NCH + c] = f2bf(acc[m][n][j] * sinvs[t]);
      }
}

// ---------------- generic bf16 MFMA GEMM: out[M][N]fp32 = Xbf[M][K] @ Wbf[N][K]^T + ba(+bb) ---
__global__ __launch_bounds__(256) void k_gemm_bf(const ushort_t* __restrict__ X, const ushort_t* __restrict__ W,
    const float* __restrict__ ba, const float* __restrict__ bb, float* __restrict__ out, int N, int K){
  __shared__ ushort_t Xs[128*40];
  __shared__ ushort_t Ws[128*40];
  int n0 = blockIdx.x*128, m0 = blockIdx.y*128;
  int tid = threadIdx.x, wave = tid>>6, lane = tid&63;
  int wr = wave>>1, wc = wave&1;
  int lr = lane & 15, lk = (lane>>4)*8;
  f32x4 acc[4][4] = {};
  for (int k0=0;k0<K;k0+=32){
    __syncthreads();
    #pragma unroll
    for (int i=0;i<2;i++){
      int c = tid + i*256, r = c>>2, kb = c&3;
      *(bf16x8*)&Xs[r*40 + kb*8] = *(const bf16x8*)(X + (size_t)(m0+r)*K + k0 + kb*8);
      *(bf16x8*)&Ws[r*40 + kb*8] = *(const bf16x8*)(W + (size_t)(n0+r)*K + k0 + kb*8);
    }
    __syncthreads();
    bf16x8 af[4], bg[4];
    #pragma unroll
    for (int m=0;m<4;m++) af[m] = *(const bf16x8*)&Xs[(wr*64 + m*16 + lr)*40 + lk];
    #pragma unroll
    for (int n=0;n<4;n++) bg[n] = *(const bf16x8*)&Ws[(wc*64 + n*16 + lr)*40 + lk];
    #pragma unroll
    for (int m=0;m<4;m++)
      #pragma unroll
      for (int n=0;n<4;n++)
        acc[m][n] = __builtin_amdgcn_mfma_f32_16x16x32_bf16(af[m], bg[n], acc[m][n], 0, 0, 0);
  }
  float bsv[4];
  #pragma unroll
  for (int n=0;n<4;n++){
    int col = n0 + wc*64 + n*16 + lr;
    bsv[n] = ba[col] + (bb ? bb[col] : 0.f);
  }
  #pragma unroll
  for (int m=0;m<4;m++)
    #pragma unroll
    for (int n=0;n<4;n++)
      #pragma unroll
      for (int j=0;j<4;j++){
        int row = m0 + wr*64 + m*16 + (lane>>4)*4 + j;
        int col = n0 + wc*64 + n*16 + lr;
        out[(size_t)row*N + col] = acc[m][n][j] + bsv[n];
      }
}

// ---------------- K7: packed normalized attention output ----------------
__global__ __launch_bounds__(256) void k_attns(const float* __restrict__ A, const float* __restrict__ S,
    const int* __restrict__ pack_b, const int* __restrict__ pack_t, float* __restrict__ outA){
  int i = blockIdx.x;
  int b = pack_b[i], t = pack_t[i];
  float is = 1.f / S[b*64 + t];
  float4 v = ((const float4*)(A + ((size_t)(b*64+t))*NHW))[threadIdx.x];
  v.x*=is; v.y*=is; v.z*=is; v.w*=is;
  ((float4*)(outA + (size_t)i*NHW))[threadIdx.x] = v;
}

// ---------------- K3: BiLSTM scan, dot2+readlane, W resident in LDS (k-major) ----------------
// 256 blocks = 128 samples x 2 dirs (full machine), 512 threads = 512 gate rows.
// Wt2[p2][g] (32 x 512 int2): 4 consecutive f16 of W row g at col 4*p2. Lane-consecutive
// g => conflict-free ds_read_b64. W loaded ONCE (128 KB); no scratch, no L2 re-stream.
__global__ __launch_bounds__(512) void k_lstm_ldsT(const float* __restrict__ Gf, const float* __restrict__ Gb,
    const f16_t* __restrict__ Whf, const f16_t* __restrict__ Whb, ushort_t* __restrict__ Clbf){
  extern __shared__ char smem[];
  int2*  Wt2   = (int2*)smem;                       // 131072 B
  float* h32   = (float*)(smem + 131072);           // 128 f32
  float* gates = (float*)(smem + 131072 + 512);     // 512 f32
  int b = blockIdx.x & 127, dir = blockIdx.x >> 7;
  const f16_t* W = dir ? Whb : Whf;                 // [512][128]
  const float* G = dir ? Gb : Gf;                   // [t][128][512] (biases folded)
  int g = threadIdx.x, lane = g & 63;
  {
    const int2* wr = (const int2*)(W + (size_t)g*128);
    #pragma unroll
    for (int p2=0;p2<32;p2++) Wt2[p2*512 + g] = wr[p2];
  }
  if (g < 128) h32[g] = 0.f;
  float c = 0.f;
  __syncthreads();
  #pragma unroll 1
  for (int t=0;t<NTIME;t++){
    int tt = dir ? (NTIME-1-t) : t;
    float gv = G[((size_t)tt*NBATCH + b)*512 + g];
    // lane l owns h pairs 2l (hpk lo path): readlane(hpk,p) = (h[2p],h[2p+1])
    float2 hp2 = *(const float2*)(h32 + 2*lane);
    int hpk = __builtin_bit_cast(int, pack2(hp2.x, hp2.y));
    float a0=0.f, a1=0.f, a2=0.f, a3=0.f;
    #pragma unroll
    for (int p2=0;p2<32;p2+=2){
      int2 w0 = Wt2[p2*512 + g];
      int2 w1 = Wt2[(p2+1)*512 + g];
      int h0 = __builtin_amdgcn_readlane(hpk, 2*p2);
      int h1 = __builtin_amdgcn_readlane(hpk, 2*p2+1);
      int h2 = __builtin_amdgcn_readlane(hpk, 2*p2+2);
      int h3 = __builtin_amdgcn_readlane(hpk, 2*p2+3);
      a0 = dot2acc(BCH(w0.x), BCH(h0), a0);
      a1 = dot2acc(BCH(w0.y), BCH(h1), a1);
      a2 = dot2acc(BCH(w1.x), BCH(h2), a2);
      a3 = dot2acc(BCH(w1.y), BCH(h3), a3);
    }
    gates[g] = gv + a0+a1+a2+a3;
    __syncthreads();
    if (g < 128){
      float gi=gates[g], gf=gates[128+g], gg=gates[256+g], go=gates[384+g];
      c = sig_(gf)*c + sig_(gi)*tanh_(gg);
      float h = sig_(go)*tanh_(c);
      h32[g] = h;
      Clbf[((size_t)tt*NBATCH + b)*NCH + dir*128 + g] = f2bf(h);
    }
    __syncthreads();
  }
}

// ---------------- K4a: xs(bf16) = [Cl_bf | emb->bf16] ----------------
__global__ __launch_bounds__(256) void k_xs(const ushort_t* __restrict__ Clbf, const float* __restrict__ emb,
    const int* __restrict__ text, ushort_t* __restrict__ xsbf){
  int idx = blockIdx.x*256 + threadIdx.x;       // 8-elem chunks: 8192 rows x 64
  int row = idx>>6, c8 = idx&63;
  int t = row>>7, b = row&127;
  bf16x8 v;
  if (c8 < 32) v = *(const bf16x8*)(Clbf + (size_t)row*NCH + c8*8);
  else {
    int cls = (t==0) ? 0 : text[b*64 + (t-1)];
    const float4* e4 = (const float4*)(emb + (size_t)cls*NCH + (c8-32)*8);
    float4 a = e4[0], bq = e4[1];
    v[0]=(short)f2bf(a.x);  v[1]=(short)f2bf(a.y);  v[2]=(short)f2bf(a.z);  v[3]=(short)f2bf(a.w);
    v[4]=(short)f2bf(bq.x); v[5]=(short)f2bf(bq.y); v[6]=(short)f2bf(bq.z); v[7]=(short)f2bf(bq.w);
  }
  *(bf16x8*)(xsbf + (size_t)row*512 + c8*8) = v;
}

// ---------------- K5: GRU scan (R8/R9-measured 151us version, structural floor) ----------------
__global__ __launch_bounds__(512, 1) void k_gru(const float* __restrict__ gx,
    const float* __restrict__ Whh_g, const float* __restrict__ bhh_g, ushort_t* __restrict__ hsbf){
  int b = blockIdx.x, t0 = threadIdx.x, lane = t0 & 63, w = t0 >> 6;
  half2_t wpA[64], wpB[64], wpC[64];
  int pidxA, pidxB, pidxC;
  int hfbA, hfbB, hfbC;

#define LOADW(WP, PIDX, HFB, S) do { \
    int c = w*3 + (S); \
    int hf = (c >= 12) ? 1 : 0; \
    int row = (c - hf*12)*64 + lane; \
    PIDX = hf*768 + row; \
    HFB  = __builtin_amdgcn_readfirstlane(hf*32); \
    const float4* wr = (const float4*)(Whh_g + (size_t)row*256 + hf*128); \
    _Pragma("unroll") \
    for (int j=0;j<32;j++){ \
      float4 v = wr[j]; \
      WP[2*j]   = pack2(v.x, v.y); \
      WP[2*j+1] = pack2(v.z, v.w); \
    } \
  } while(0)

  LOADW(wpA, pidxA, hfbA, 0);
  LOADW(wpB, pidxB, hfbB, 1);
  LOADW(wpC, pidxC, hfbC, 2);
#undef LOADW

  __shared__ float h32[256];
  __shared__ float partLds[1536];
  __shared__ float bhL[768];
  if (t0 < 256) h32[t0] = 0.f;
  bhL[t0] = bhh_g[t0];
  if (t0 < 256) bhL[512+t0] = bhh_g[512+t0];
  float hprev = 0.f;
  __syncthreads();
  #pragma unroll 1
  for (int t=0;t<NTIME;t++){
    float gxr=0.f, gxz=0.f, gxn=0.f;
    if (t0 < 256){
      const float* gxp = gx + ((size_t)t*NBATCH + b)*768;
      gxr = gxp[t0]; gxz = gxp[256+t0]; gxn = gxp[512+t0];
    }
    float4 hq = *(const float4*)(h32 + 4*lane);
    int hpk0 = __builtin_bit_cast(int, pack2(hq.x, hq.y));
    int hpk1 = __builtin_bit_cast(int, pack2(hq.z, hq.w));

#define DOTASK(WP, PIDX, HFB) do { \
    float a0=0.f, a1=0.f, a2=0.f, a3=0.f; \
    _Pragma("unroll") \
    for (int jj=0;jj<64;jj+=2){ \
      int hv0 = __builtin_amdgcn_readlane(hpk0, HFB + (jj>>1)); \
      int hv1 = __builtin_amdgcn_readlane(hpk1, HFB + (jj>>1)); \
      if ((jj>>1)&1){ \
        a2 = dot2acc(WP[jj],   __builtin_bit_cast(half2_t, hv0), a2); \
        a3 = dot2acc(WP[jj+1], __builtin_bit_cast(half2_t, hv1), a3); \
      } else { \
        a0 = dot2acc(WP[jj],   __builtin_bit_cast(half2_t, hv0), a0); \
        a1 = dot2acc(WP[jj+1], __builtin_bit_cast(half2_t, hv1), a1); \
      } \
    } \
    partLds[PIDX] = a0+a1+a2+a3; \
  } while(0)

    DOTASK(wpA, pidxA, hfbA);
    DOTASK(wpB, pidxB, hfbB);
    DOTASK(wpC, pidxC, hfbC);
#undef DOTASK

    __syncthreads();
    if (t0 < 256){
      float rh = bhL[t0]     + partLds[t0]     + partLds[768+t0];
      float zh = bhL[256+t0] + partLds[256+t0] + partLds[1024+t0];
      float nh = bhL[512+t0] + partLds[512+t0] + partLds[1280+t0];
      float r = sig_(gxr + rh);
      float z = sig_(gxz + zh);
      float n = tanh_(gxn + r*nh);
      float h = (1.f-z)*n + z*hprev;
      hprev = h;
      h32[t0] = h;
      hsbf[((size_t)t*NBATCH + b)*NCH + t0] = f2bf(h);
    }
    __syncthreads();
  }
}

// ---------------- K6: logits via MFMA with row gather ----------------
__global__ __launch_bounds__(256) void k_logits_mfma(const ushort_t* __restrict__ hsbf,
    const int* __restrict__ pack_t, const int* __restrict__ pack_b,
    const ushort_t* __restrict__ Wbf, const float* __restrict__ bias,
    float* __restrict__ out, int L){
  __shared__ ushort_t Xs[64*40];
  __shared__ ushort_t Ws[128*40];
  __shared__ int rrow[64];
  int m0 = blockIdx.x*64;
  int tid = threadIdx.x, wave = tid>>6, lane = tid&63;
  int lr = lane & 15, lk = (lane>>4)*8;
  if (tid < 64){
    int m = m0 + tid;
    int pt = (m<L) ? pack_t[m] : 0;
    int pb = (m<L) ? pack_b[m] : 0;
    rrow[tid] = pt*NBATCH + pb;
  }
  f32x4 acc[4][2] = {};
  for (int k0=0;k0<NCH;k0+=32){
    __syncthreads();
    {
      int r = tid>>2, kb = tid&3;
      *(bf16x8*)&Xs[r*40 + kb*8] = *(const bf16x8*)(hsbf + (size_t)rrow[r]*NCH + k0 + kb*8);
    }
    #pragma unroll
    for (int i=0;i<2;i++){
      int c = tid + i*256, r = c>>2, kb = c&3;
      *(bf16x8*)&Ws[r*40 + kb*8] = *(const bf16x8*)(Wbf + (size_t)r*NCH + k0 + kb*8);
    }
    __syncthreads();
    bf16x8 af[4], bg[2];
    #pragma unroll
    for (int m=0;m<4;m++) af[m] = *(const bf16x8*)&Xs[(m*16 + lr)*40 + lk];
    #pragma unroll
    for (int n=0;n<2;n++) bg[n] = *(const bf16x8*)&Ws[(wave*32 + n*16 + lr)*40 + lk];
    #pragma unroll
    for (int m=0;m<4;m++)
      #pragma unroll
      for (int n=0;n<2;n++)
        acc[m][n] = __builtin_amdgcn_mfma_f32_16x16x32_bf16(af[m], bg[n], acc[m][n], 0, 0, 0);
  }
  #pragma unroll
  for (int m=0;m<4;m++)
    #pragma unroll
    for (int n=0;n<2;n++)
      #pragma unroll
      for (int j=0;j<4;j++){
        int row = m0 + m*16 + (lane>>4)*4 + j;
        int col = wave*32 + n*16 + lr;
        if (row < L) out[(size_t)row*NCLS + col] = acc[m][n][j] + bias[col];
      }
}

extern "C" void kernel_launch(void* const* d_in, const int* in_sizes, int n_in,
                              void* d_out, int out_size, void* d_ws, size_t ws_size,
                              hipStream_t stream) {
  const float* feature = (const float*)d_in[0];
  const float* A       = (const float*)d_in[1];
  const int*   text    = (const int*)d_in[2];
  const int*   pack_b  = (const int*)d_in[4];
  const int*   pack_t  = (const int*)d_in[5];
  const float* emb     = (const float*)d_in[6];
  const float* Wih_f   = (const float*)d_in[7];
  const float* Whh_f   = (const float*)d_in[8];
  const float* bih_f   = (const float*)d_in[9];
  const float* bhh_f   = (const float*)d_in[10];
  const float* Wih_b   = (const float*)d_in[11];
  const float* Whh_b   = (const float*)d_in[12];
  const float* bih_b   = (const float*)d_in[13];
  const float* bhh_b   = (const float*)d_in[14];
  const float* Wih_g   = (const float*)d_in[15];
  const float* Whh_g   = (const float*)d_in[16];
  const float* bih_g   = (const float*)d_in[17];
  const float* bhh_g   = (const float*)d_in[18];
  const float* Wgen    = (const float*)d_in[19];
  const float* bgen    = (const float*)d_in[20];
  int L = in_sizes[4];

  char* ws = (char*)d_ws;
  const size_t KB = 1024, MB = 1u<<20;
  float*    S       = (float*)(ws + 0);                    // 32 KB
  ushort_t* Wf_bf   = (ushort_t*)(ws + 1*MB);              // 256 KB
  ushort_t* Wb_bf   = (ushort_t*)(ws + 1*MB + 256*KB);     // 256 KB
  ushort_t* Wg_bf   = (ushort_t*)(ws + 1*MB + 512*KB);     // 768 KB
  ushort_t* Wgen_bf = (ushort_t*)(ws + 1*MB + 1280*KB);    // 64 KB
  f16_t*    Whf_h   = (f16_t*)(ws + 2*MB + 512*KB);        // 128 KB
  f16_t*    Whb_h   = (f16_t*)(ws + 2*MB + 640*KB);        // 128 KB
  ushort_t* Cbf     = (ushort_t*)(ws + 4*MB);              // 4 MB  [t][b][256]
  ushort_t* Clbf    = (ushort_t*)(ws + 8*MB);              // 4 MB
  ushort_t* hsbf    = (ushort_t*)(ws + 12*MB);             // 4 MB
  float*    Gf      = (float*)(ws + 16*MB);                // 16 MB (dead after k_lstm)
  float*    Gb      = (float*)(ws + 32*MB);                // 16 MB (dead after k_lstm)
  ushort_t* xsbf    = (ushort_t*)(ws + 16*MB);             // 8 MB, aliases Gf
  float*    gx      = (float*)(ws + 24*MB);                // 25.2 MB, aliases Gb+

  float* out_res   = (float*)d_out;
  float* out_attns = out_res + (size_t)L*NCLS;

  const int LSTM_SMEM = 131072 + 512 + 2048;               // 133,632 B
  (void)hipFuncSetAttribute((const void*)k_lstm_ldsT,
                            hipFuncAttributeMaxDynamicSharedMemorySize, LSTM_SMEM);

  k_convw<<<512, 256, 0, stream>>>(Wih_f, Wf_bf, 512*256);
  k_convw<<<512, 256, 0, stream>>>(Wih_b, Wb_bf, 512*256);
  k_convw<<<1536, 256, 0, stream>>>(Wih_g, Wg_bf, 768*512);
  k_convw<<<128, 256, 0, stream>>>(Wgen, Wgen_bf, 128*256);
  k_convh<<<256, 256, 0, stream>>>(Whh_f, Whf_h, 512*128);
  k_convh<<<256, 256, 0, stream>>>(Whh_b, Whb_h, 512*128);
  k_rowsum<<<8192, 256, 0, stream>>>(A, S);
  k_pool_mfma<<<256, 256, 0, stream>>>(feature, A, S, Cbf);
  k_attns<<<L, 256, 0, stream>>>(A, S, pack_b, pack_t, out_attns);
  k_gemm_bf<<<dim3(4,64), 256, 0, stream>>>(Cbf, Wf_bf, bih_f, bhh_f, Gf, 512, 256);
  k_gemm_bf<<<dim3(4,64), 256, 0, stream>>>(Cbf, Wb_bf, bih_b, bhh_b, Gb, 512, 256);
  k_lstm_ldsT<<<256, 512, LSTM_SMEM, stream>>>(Gf, Gb, Whf_h, Whb_h, Clbf);
  k_xs<<<2048, 256, 0, stream>>>(Clbf, emb, text, xsbf);
  k_gemm_bf<<<dim3(6,64), 256, 0, stream>>>(xsbf, Wg_bf, bih_g, nullptr, gx, 768, 512);
  k_gru<<<128, 512, 0, stream>>>(gx, Whh_g, bhh_g, hsbf);
  k_logits_mfma<<<(L+63)/64, 256, 0, stream>>>(hsbf, pack_t, pack_b, Wgen_bf, bgen, out_res, L);
}